// Round 12
// baseline (60.859 us; speedup 1.0000x reference)
//
#include <hip/hip_runtime.h>
#include <math.h>

// Problem constants (fixed by the reference setup)
#define NN 16
#define CC 85
#define HH 160
#define WW 160
#define HW_ 25600            // H*W
#define NHW 409600           // N*H*W
#define TB 256
#define GRIDN 400            // NHW/4/TB: one float4 cell per thread
#define MAGICA 0x11C0FFEE    // anchor Phase-A done
#define MAGICD 0x22C0FFEE    // block fully done

__device__ __forceinline__ float wave_sum(float v) {
#pragma unroll
  for (int o = 32; o; o >>= 1) v += __shfl_down(v, o, 64);
  return v;
}

__device__ __forceinline__ float sl1(float d) {
  float ad = fabsf(d);
  return (ad < 1.f) ? 0.5f * d * d : (ad - 0.5f);
}

// SIoU variant from the reference (_bbox_iou)
__device__ __forceinline__ float siou(float pcx, float pcy, float pw, float ph,
                                      float gcx, float gcy, float gw, float gh) {
  const float eps = 1e-7f;
  float b1x1 = pcx - pw * 0.5f, b1x2 = pcx + pw * 0.5f;
  float b1y1 = pcy - ph * 0.5f, b1y2 = pcy + ph * 0.5f;
  float b2x1 = gcx - gw * 0.5f, b2x2 = gcx + gw * 0.5f;
  float b2y1 = gcy - gh * 0.5f, b2y2 = gcy + gh * 0.5f;
  float inter = fmaxf(fminf(b1x2, b2x2) - fmaxf(b1x1, b2x1), 0.f) *
                fmaxf(fminf(b1y2, b2y2) - fmaxf(b1y1, b2y1), 0.f);
  float w1 = b1x2 - b1x1, h1 = b1y2 - b1y1 + eps;
  float w2 = b2x2 - b2x1, h2 = b2y2 - b2y1 + eps;
  float uni = w1 * h1 + w2 * h2 - inter + eps;
  float iou = inter / uni;
  float cw = fmaxf(b1x2, b2x2) - fminf(b1x1, b2x1);
  float ch = fmaxf(b1y2, b2y2) - fminf(b1y1, b2y1);
  float s_cw = (b2x1 + b2x2 - b1x1 - b1x2) * 0.5f;
  float s_ch = (b2y1 + b2y2 - b1y1 - b1y2) * 0.5f;
  float sigma = sqrtf(s_cw * s_cw + s_ch * s_ch);
  float sin_a1 = fabsf(s_cw) / sigma;
  float sin_a2 = fabsf(s_ch) / sigma;
  float sin_a = (sin_a1 > 0.70710678f) ? sin_a2 : sin_a1;
  // cos(2*asin(x) - pi/2) == 2*x*sqrt(1-x^2)
  float angle_cost = 2.f * sin_a * sqrtf(fmaxf(1.f - sin_a * sin_a, 0.f));
  float rx = s_cw / cw; rx *= rx;
  float ry = s_ch / ch; ry *= ry;
  float gamma = angle_cost - 2.f;
  float dist = 2.f - expf(gamma * rx) - expf(gamma * ry);
  float ow = fabsf(w1 - w2) / fmaxf(w1, w2);
  float oh = fabsf(h1 - h2) / fmaxf(h1, h2);
  float e1 = 1.f - expf(-ow), e2 = 1.f - expf(-oh);
  float s1 = e1 * e1; s1 *= s1;
  float s2 = e2 * e2; s2 *= s2;
  return iou - 0.5f * (dist + s1 + s2);
}

// Single kernel. One cheap sync on the critical path: the 64 anchor blocks
// (co-dispatched peers doing identical work) flag-barrier among THEMSELVES
// only — the 336 cell blocks are never waited on except by block 0's final
// sweep (by which time they finished long ago). No global accumulators, no
// zero-init: magic flags work from any initial contents and are cleared by
// the finalizer for the next graph replay.
__global__ __launch_bounds__(TB)
void fused(const float* __restrict__ preds, const float* __restrict__ targets,
           int M, int* __restrict__ winner, float* __restrict__ iou_arr,
           int* __restrict__ flagsA, int* __restrict__ flagsD,
           float* __restrict__ partA_iou, float* __restrict__ partA_cnt,
           float* __restrict__ part_obj, float4* __restrict__ partB,
           int* __restrict__ hist16, float* __restrict__ corrA16,
           float* __restrict__ out) {
  const int tid = threadIdx.x, bid = blockIdx.x;
  const int t = bid * TB + tid;
  const int lane = tid & 63, wid = tid >> 6;
  const int M4 = 4 * M;
  const int nact = (M4 + TB - 1) / TB;       // 64 anchor blocks
  const bool anchorblk = bid < nact;

  __shared__ float sh0[4], sh1[4], sh2[4], sh3[4];
  __shared__ int hist[NN];
  __shared__ float corrA[NN];
  __shared__ float s_mean;

  // ================= Phase A =================
  // cells: one float4 per thread (tobj=0 / factor=0.75 folded out)
  float objs;
  {
    int i0 = t * 4;
    int b = i0 / HW_;
    int r = i0 - b * HW_;                    // HW_ % 4 == 0
    float4 p4 = *reinterpret_cast<const float4*>(preds + (size_t)b * CC * HW_ + r);
    objs = sl1(p4.x) + sl1(p4.y) + sl1(p4.z) + sl1(p4.w);
  }

  // anchors (blocks 0..63, alongside cell work): state stays in REGISTERS;
  // only iou_arr is published (needed for the telescoping old-winner lookup)
  float iou_v = 0.f, mf = 0.f, pobj = 0.f, nllv = 0.f;
  int ab = 0, aidx = 0;
  bool am = false;
  if (anchorblk && t < M4) {
    int mm = t % M, q = t / M;
    const float* t6 = targets + (size_t)mm * 6;
    ab = (int)t6[0];
    int acls = (int)t6[1];
    float gx = t6[2] * (float)WW, gy = t6[3] * (float)HH;
    float gw = t6[4] * (float)WW, gh = t6[5] * (float)HH;
    int gi = (int)gx + (q & 1);
    int gj = (int)gy + (q >> 1);
    am = (gi >= 1) && (gi < WW) && (gj >= 1) && (gj < HH);
    if (am) {
      const float* p = preds + (size_t)ab * CC * HW_ + (size_t)gj * WW + gi;
      pobj = p[0];
      float p1 = p[(size_t)1 * HW_];
      float p2 = p[(size_t)2 * HW_];
      float p3 = p[(size_t)3 * HW_];
      float p4v = p[(size_t)4 * HW_];
      float pc = p[(size_t)(5 + acls) * HW_];
      float px = tanhf(p1) + (float)gi;
      float py = tanhf(p2) + (float)gj;
      float pw = (1.f / (1.f + expf(-p3))) * (float)WW;
      float ph = (1.f / (1.f + expf(-p4v))) * (float)HH;
      iou_v = siou(px, py, pw, ph, gx, gy, gw, gh);
      nllv = -logf(pc);
      mf = 1.f;
      aidx = ab * HW_ + gj * WW + gi;
      winner[aidx] = -1;                     // scatter-init only cells used
    }
    iou_arr[t] = iou_v;
  }

  if (tid < NN) { hist[tid] = 0; corrA[tid] = 0.f; }
  {
    float o = wave_sum(objs), s = wave_sum(iou_v), c = wave_sum(mf);
    if (lane == 0) { sh0[wid] = o; sh1[wid] = s; sh2[wid] = c; }
  }
  __syncthreads();
  if (tid == 0) {
    part_obj[bid] = sh0[0] + sh0[1] + sh0[2] + sh0[3];
    if (anchorblk) {
      partA_iou[bid] = sh1[0] + sh1[1] + sh1[2] + sh1[3];
      partA_cnt[bid] = sh2[0] + sh2[1] + sh2[2] + sh2[3];
    }
  }
  __syncthreads();
  __threadfence();                           // publish Phase-A stores

  if (!anchorblk) {
    if (tid == 0)
      __hip_atomic_store(&flagsD[bid], MAGICD, __ATOMIC_RELEASE,
                         __HIP_MEMORY_SCOPE_AGENT);
    return;                                  // cell blocks done — free the CU
  }

  // ---- peer barrier among the 64 anchor blocks only (skew ~ sub-µs) ----
  if (tid == 0)
    __hip_atomic_store(&flagsA[bid], MAGICA, __ATOMIC_RELEASE,
                       __HIP_MEMORY_SCOPE_AGENT);
  for (;;) {
    int ok = (tid < nact)
      ? (__hip_atomic_load(&flagsA[tid], __ATOMIC_ACQUIRE,
                           __HIP_MEMORY_SCOPE_AGENT) == MAGICA) : 1;
    if (__syncthreads_and(ok)) break;
    __builtin_amdgcn_s_sleep(1);
  }

  // ================= Phase B (anchor blocks) =================
  {
    float si = (tid < nact) ? partA_iou[tid] : 0.f;
    float sc = (tid < nact) ? partA_cnt[tid] : 0.f;
    si = wave_sum(si); sc = wave_sum(sc);
    if (tid == 0) s_mean = si / fmaxf(sc, 1.f);
  }
  __syncthreads();
  const float iou_mean = s_mean;

  float fc = 0.f, li = 0.f, nl = 0.f, cB = 0.f;
  if (am && iou_v > iou_mean) {
    fc = 1.f;
    li = 1.f - iou_v;
    nl = nllv;
    atomicAdd(&hist[ab], 1);
    int old = atomicMax(&winner[aidx], t);   // device-coherent
    if (old < t) {                   // raised the max (old==-1 or smaller)
      float dA = sl1(pobj - iou_v);  // A(t)
      if (old >= 0) {
        dA -= sl1(pobj - iou_arr[old]);      // same cell -> same pobj
      } else {
        cB = -0.75f * sl1(pobj);             // first claimant pays B once
      }
      atomicAdd(&corrA[ab], dA);     // telescopes to A(final winner)
    }
  }
  fc = wave_sum(fc); li = wave_sum(li); nl = wave_sum(nl); cB = wave_sum(cB);
  if (lane == 0) { sh0[wid] = fc; sh1[wid] = li; sh2[wid] = nl; sh3[wid] = cB; }
  __syncthreads();
  if (tid == 0)
    partB[bid] = make_float4(sh0[0] + sh0[1] + sh0[2] + sh0[3],
                             sh1[0] + sh1[1] + sh1[2] + sh1[3],
                             sh2[0] + sh2[1] + sh2[2] + sh2[3],
                             sh3[0] + sh3[1] + sh3[2] + sh3[3]);
  if (tid < NN) {
    hist16[bid * NN + tid] = hist[tid];
    corrA16[bid * NN + tid] = corrA[tid];
  }
  __syncthreads();
  __threadfence();
  if (tid == 0)
    __hip_atomic_store(&flagsD[bid], MAGICD, __ATOMIC_RELEASE,
                       __HIP_MEMORY_SCOPE_AGENT);
  if (bid != 0) return;

  // ================= Finalize (block 0) =================
  // Cell blocks finished long ago; anchor peers just signaled. 1-2 rounds.
  for (;;) {
    int ok = 1;
    for (int i = tid; i < GRIDN; i += TB)
      if (__hip_atomic_load(&flagsD[i], __ATOMIC_ACQUIRE,
                            __HIP_MEMORY_SCOPE_AGENT) != MAGICD) ok = 0;
    if (__syncthreads_and(ok)) break;
    __builtin_amdgcn_s_sleep(1);
  }

  // per-batch correction (tid<16): nperb + corrA totals, fixed order
  float corr_b = 0.f;
  if (tid < NN) {
    int np = 0; float ca = 0.f;
    for (int j = 0; j < nact; ++j) {
      np += hist16[j * NN + tid];
      ca += corrA16[j * NN + tid];
    }
    if (np > 0) corr_b = ca * ((float)HW_ / (float)np * 0.25f);
  }
  // partB totals + obj_base, fixed-order trees
  float cf = 0.f, lit = 0.f, nlt = 0.f, cBt = 0.f, ob = 0.f;
  for (int i = tid; i < nact; i += TB) {
    float4 pb = partB[i];
    cf += pb.x; lit += pb.y; nlt += pb.z; cBt += pb.w;
  }
  for (int i = tid; i < GRIDN; i += TB) ob += part_obj[i];

  corr_b = wave_sum(corr_b); cf = wave_sum(cf); lit = wave_sum(lit);
  nlt = wave_sum(nlt); cBt = wave_sum(cBt); ob = wave_sum(ob);
  __shared__ float fin[6][4];
  if (lane == 0) {
    fin[0][wid] = corr_b; fin[1][wid] = cf; fin[2][wid] = lit;
    fin[3][wid] = nlt; fin[4][wid] = cBt; fin[5][wid] = ob;
  }
  __syncthreads();
  if (tid == 0) {
    float corr = fin[0][0] + fin[0][1] + fin[0][2] + fin[0][3]
               + fin[4][0] + fin[4][1] + fin[4][2] + fin[4][3];
    float cft  = fin[1][0] + fin[1][1] + fin[1][2] + fin[1][3];
    float litt = fin[2][0] + fin[2][1] + fin[2][2] + fin[2][3];
    float nltt = fin[3][0] + fin[3][1] + fin[3][2] + fin[3][3];
    float obt  = fin[5][0] + fin[5][1] + fin[5][2] + fin[5][3];
    float cff = fmaxf(cft, 1.f);
    float iou_loss = litt / cff;
    float cls_loss = nltt / cff;
    float obj_loss = (0.75f * obt + corr) / (float)NHW;
    out[0] = iou_loss;
    out[1] = obj_loss;
    out[2] = cls_loss;
    out[3] = iou_loss * 8.f + obj_loss * 16.f + cls_loss;
  }
  // clear flags for the next graph replay (all other blocks have exited;
  // replays are serialized, so no cross-replay race)
  __syncthreads();
  for (int i = tid; i < GRIDN; i += TB) flagsD[i] = 0;
  if (tid < nact) flagsA[tid] = 0;
}

extern "C" void kernel_launch(void* const* d_in, const int* in_sizes, int n_in,
                              void* d_out, int out_size, void* d_ws, size_t ws_size,
                              hipStream_t stream) {
  const float* preds = (const float*)d_in[0];
  const float* targets = (const float*)d_in[1];
  int M = in_sizes[1] / 6;             // 4096
  int M4 = 4 * M;                      // 16384
  int nact = (M4 + TB - 1) / TB;       // 64

  char* ws = (char*)d_ws;
  size_t off = 0;
  int* winner = (int*)(ws + off);        off += (size_t)NHW * 4;        // 1.6 MB
  float* iou_arr = (float*)(ws + off);   off += (size_t)M4 * 4;         // 64 KB
  int* flagsA = (int*)(ws + off);        off += ((size_t)nact * 4 + 255) & ~(size_t)255;
  int* flagsD = (int*)(ws + off);        off += ((size_t)GRIDN * 4 + 255) & ~(size_t)255;
  float* partA_iou = (float*)(ws + off); off += ((size_t)nact * 4 + 255) & ~(size_t)255;
  float* partA_cnt = (float*)(ws + off); off += ((size_t)nact * 4 + 255) & ~(size_t)255;
  float* part_obj = (float*)(ws + off);  off += ((size_t)GRIDN * 4 + 255) & ~(size_t)255;
  float4* partB = (float4*)(ws + off);   off += (size_t)nact * 16;
  int* hist16 = (int*)(ws + off);        off += ((size_t)nact * NN * 4 + 255) & ~(size_t)255;
  float* corrA16 = (float*)(ws + off);   off += ((size_t)nact * NN * 4 + 255) & ~(size_t)255;

  fused<<<GRIDN, TB, 0, stream>>>(preds, targets, M, winner, iou_arr,
                                  flagsA, flagsD, partA_iou, partA_cnt,
                                  part_obj, partB, hist16, corrA16,
                                  (float*)d_out);
}

// Round 13
// 18.632 us; speedup vs baseline: 3.2664x; 3.2664x over previous
//
#include <hip/hip_runtime.h>
#include <math.h>

// Problem constants (fixed by the reference setup)
#define NN 16
#define CC 85
#define HH 160
#define WW 160
#define HW_ 25600            // H*W
#define NHW 409600           // N*H*W
#define TB 256
#define CELLB 400            // cell blocks: NHW/4/TB, one float4 cell per thread

struct Accum {               // zeroed by K1; visible to K2 via kernel boundary
  float cnt_f, liou, nll, corrB;
  float corrA[NN];
  int nperb[NN];
  int done;
};

__device__ __forceinline__ float wave_sum(float v) {
#pragma unroll
  for (int o = 32; o; o >>= 1) v += __shfl_down(v, o, 64);
  return v;
}

__device__ __forceinline__ float sl1(float d) {
  float ad = fabsf(d);
  return (ad < 1.f) ? 0.5f * d * d : (ad - 0.5f);
}

// SIoU variant from the reference (_bbox_iou)
__device__ __forceinline__ float siou(float pcx, float pcy, float pw, float ph,
                                      float gcx, float gcy, float gw, float gh) {
  const float eps = 1e-7f;
  float b1x1 = pcx - pw * 0.5f, b1x2 = pcx + pw * 0.5f;
  float b1y1 = pcy - ph * 0.5f, b1y2 = pcy + ph * 0.5f;
  float b2x1 = gcx - gw * 0.5f, b2x2 = gcx + gw * 0.5f;
  float b2y1 = gcy - gh * 0.5f, b2y2 = gcy + gh * 0.5f;
  float inter = fmaxf(fminf(b1x2, b2x2) - fmaxf(b1x1, b2x1), 0.f) *
                fmaxf(fminf(b1y2, b2y2) - fmaxf(b1y1, b2y1), 0.f);
  float w1 = b1x2 - b1x1, h1 = b1y2 - b1y1 + eps;
  float w2 = b2x2 - b2x1, h2 = b2y2 - b2y1 + eps;
  float uni = w1 * h1 + w2 * h2 - inter + eps;
  float iou = inter / uni;
  float cw = fmaxf(b1x2, b2x2) - fminf(b1x1, b2x1);
  float ch = fmaxf(b1y2, b2y2) - fminf(b1y1, b2y1);
  float s_cw = (b2x1 + b2x2 - b1x1 - b1x2) * 0.5f;
  float s_ch = (b2y1 + b2y2 - b1y1 - b1y2) * 0.5f;
  float sigma = sqrtf(s_cw * s_cw + s_ch * s_ch);
  float sin_a1 = fabsf(s_cw) / sigma;
  float sin_a2 = fabsf(s_ch) / sigma;
  float sin_a = (sin_a1 > 0.70710678f) ? sin_a2 : sin_a1;
  // cos(2*asin(x) - pi/2) == 2*x*sqrt(1-x^2)
  float angle_cost = 2.f * sin_a * sqrtf(fmaxf(1.f - sin_a * sin_a, 0.f));
  float rx = s_cw / cw; rx *= rx;
  float ry = s_ch / ch; ry *= ry;
  float gamma = angle_cost - 2.f;
  float dist = 2.f - expf(gamma * rx) - expf(gamma * ry);
  float ow = fabsf(w1 - w2) / fmaxf(w1, w2);
  float oh = fabsf(h1 - h2) / fmaxf(h1, h2);
  float e1 = 1.f - expf(-ow), e2 = 1.f - expf(-oh);
  float s1 = e1 * e1; s1 *= s1;
  float s2 = e2 * e2; s2 *= s2;
  return iou - 0.5f * (dist + s1 + s2);
}

// K1, decoupled roles with anchors dispatched FIRST (blocks 0..63: the
// latency-heavy scattered gathers start earliest), cells in blocks 64..463.
// Critical path = max(anchors, cells), not sum — no straggler blocks.
__global__ __launch_bounds__(TB)
void k1(const float* __restrict__ preds, const float* __restrict__ targets,
        int M, Accum* __restrict__ acc, int* __restrict__ winner,
        float4* __restrict__ state4,
        float* __restrict__ partA_iou, float* __restrict__ partA_cnt,
        float* __restrict__ part_obj) {
  const int tid = threadIdx.x, bid = blockIdx.x;
  const int lane = tid & 63, wid = tid >> 6;
  const int M4 = 4 * M;
  const int nact = (M4 + TB - 1) / TB;       // 64
  __shared__ float sh0[4], sh1[4];

  if (bid == 0 && tid == 0) {
    acc->cnt_f = 0.f; acc->liou = 0.f; acc->nll = 0.f; acc->corrB = 0.f;
    for (int i = 0; i < NN; ++i) { acc->corrA[i] = 0.f; acc->nperb[i] = 0; }
    acc->done = 0;
  }

  if (bid < nact) {
    // ---- anchors: decode + 6 gathers + SIoU + nll ----
    const int t = bid * TB + tid;
    float iou_v = 0.f, mf = 0.f;
    float pobj = 0.f, nllv = 0.f;
    int meta = 0;
    if (t < M4) {
      int mm = t % M, q = t / M;
      const float* t6 = targets + (size_t)mm * 6;
      int ab = (int)t6[0];
      int acls = (int)t6[1];
      float gx = t6[2] * (float)WW, gy = t6[3] * (float)HH;
      float gw = t6[4] * (float)WW, gh = t6[5] * (float)HH;
      int gi = (int)gx + (q & 1);
      int gj = (int)gy + (q >> 1);
      bool am = (gi >= 1) && (gi < WW) && (gj >= 1) && (gj < HH);
      if (am) {
        const float* p = preds + (size_t)ab * CC * HW_ + (size_t)gj * WW + gi;
        pobj = p[0];
        float p1 = p[(size_t)1 * HW_];
        float p2 = p[(size_t)2 * HW_];
        float p3 = p[(size_t)3 * HW_];
        float p4v = p[(size_t)4 * HW_];
        float pc = p[(size_t)(5 + acls) * HW_];
        float px = tanhf(p1) + (float)gi;
        float py = tanhf(p2) + (float)gj;
        float pw = (1.f / (1.f + expf(-p3))) * (float)WW;
        float ph = (1.f / (1.f + expf(-p4v))) * (float)HH;
        iou_v = siou(px, py, pw, ph, gx, gy, gw, gh);
        nllv = -logf(pc);
        mf = 1.f;
        int aidx = ab * HW_ + gj * WW + gi;
        winner[aidx] = -1;                   // scatter-init only cells used
        meta = 1 | (ab << 1) | (aidx << 5);  // aidx < 2^19 -> fits
      }
      state4[t] = make_float4(iou_v, pobj, nllv, __int_as_float(meta));
    }
    float s = wave_sum(iou_v), c = wave_sum(mf);
    if (lane == 0) { sh0[wid] = s; sh1[wid] = c; }
    __syncthreads();
    if (tid == 0) {
      partA_iou[bid] = sh0[0] + sh0[1] + sh0[2] + sh0[3];
      partA_cnt[bid] = sh1[0] + sh1[1] + sh1[2] + sh1[3];
    }
  } else {
    // ---- cells: one float4 per thread (tobj=0 / factor=0.75 folded out) ----
    const int cbid = bid - nact;
    int i0 = (cbid * TB + tid) * 4;
    int b = i0 / HW_;
    int r = i0 - b * HW_;                    // HW_ % 4 == 0
    float4 p4 = *reinterpret_cast<const float4*>(preds + (size_t)b * CC * HW_ + r);
    float objs = sl1(p4.x) + sl1(p4.y) + sl1(p4.z) + sl1(p4.w);
    float o = wave_sum(objs);
    if (lane == 0) sh0[wid] = o;
    __syncthreads();
    if (tid == 0) part_obj[cbid] = sh0[0] + sh0[1] + sh0[2] + sh0[3];
  }
}

// K2 (64 blocks, ZERO waits): telescoping atomicMax correction resolves the
// per-cell winner algebraically in one pass; per-batch buckets defer the
// nperb factor; the LAST block to arrive at the done-counter finalizes.
__global__ __launch_bounds__(TB)
void k2(const float4* __restrict__ state4, int* __restrict__ winner,
        const float* __restrict__ partA_iou, const float* __restrict__ partA_cnt,
        const float* __restrict__ part_obj, Accum* __restrict__ acc,
        int M, int nact, float* __restrict__ out) {
  const int tid = threadIdx.x, bid = blockIdx.x;
  const int t = bid * TB + tid;
  const int lane = tid & 63, wid = tid >> 6;
  const int M4 = 4 * M;

  __shared__ float r0[4], r1[4], r2[4], r3[4];
  __shared__ int hist[NN];
  __shared__ float corrA[NN];
  __shared__ float s_mean;
  __shared__ int lastflag;
  if (tid < NN) { hist[tid] = 0; corrA[tid] = 0.f; }

  // ---- iou_mean: fixed-order reduce of the 64 anchor partials (wave 0) ----
  {
    float si = (tid < nact) ? partA_iou[tid] : 0.f;
    float sc = (tid < nact) ? partA_cnt[tid] : 0.f;
    si = wave_sum(si); sc = wave_sum(sc);
    if (tid == 0) s_mean = si / fmaxf(sc, 1.f);
  }
  __syncthreads();
  const float iou_mean = s_mean;

  // ---- single filter pass with telescoping correction ----
  float fc = 0.f, li = 0.f, nl = 0.f, cB = 0.f;
  if (t < M4) {
    float4 s4 = state4[t];
    int meta = __float_as_int(s4.w);
    if ((meta & 1) && s4.x > iou_mean) {
      int b = (meta >> 1) & 15;
      fc = 1.f;
      li = 1.f - s4.x;
      nl = s4.z;
      atomicAdd(&hist[b], 1);
      int old = atomicMax(&winner[meta >> 5], t);
      if (old < t) {                   // raised the max (old==-1 or smaller)
        float dA = sl1(s4.y - s4.x);   // A(t) = sl1(pobj - iou_t)
        if (old >= 0) {
          dA -= sl1(s4.y - state4[old].x);     // same cell -> same pobj
        } else {
          cB = -0.75f * sl1(s4.y);             // first claimant pays B once
        }
        atomicAdd(&corrA[b], dA);      // telescopes to A(final winner)
      }
    }
  }
  fc = wave_sum(fc); li = wave_sum(li); nl = wave_sum(nl); cB = wave_sum(cB);
  if (lane == 0) { r0[wid] = fc; r1[wid] = li; r2[wid] = nl; r3[wid] = cB; }
  __syncthreads();
  if (tid == 0) {
    atomicAdd(&acc->cnt_f, r0[0] + r0[1] + r0[2] + r0[3]);
    atomicAdd(&acc->liou,  r1[0] + r1[1] + r1[2] + r1[3]);
    atomicAdd(&acc->nll,   r2[0] + r2[1] + r2[2] + r2[3]);
    atomicAdd(&acc->corrB, r3[0] + r3[1] + r3[2] + r3[3]);
  }
  if (tid < NN) {
    if (hist[tid] > 0) atomicAdd(&acc->nperb[tid], hist[tid]);
    if (corrA[tid] != 0.f) atomicAdd(&acc->corrA[tid], corrA[tid]);
  }

  // ---- last-done block finalizes (nobody ever waits) ----
  __syncthreads();   // barrier semantics drain the block's outstanding atomics
  if (tid == 0) {
    int prev = __hip_atomic_fetch_add(&acc->done, 1, __ATOMIC_ACQ_REL,
                                      __HIP_MEMORY_SCOPE_AGENT);
    lastflag = (prev == nact - 1) ? 1 : 0;
  }
  __syncthreads();
  if (!lastflag) return;

  // obj_base: 400 cell partials (K1-written; kernel boundary => visible)
  float ob = 0.f;
  for (int i = tid; i < CELLB; i += TB) ob += part_obj[i];
  ob = wave_sum(ob);
  if (lane == 0) r0[wid] = ob;

  // per-batch correction: corrA_total[b] * fval(b)
  float corr_b = 0.f;
  if (tid < NN) {
    int np = __hip_atomic_load(&acc->nperb[tid], __ATOMIC_RELAXED,
                               __HIP_MEMORY_SCOPE_AGENT);
    float ca = __hip_atomic_load(&acc->corrA[tid], __ATOMIC_RELAXED,
                                 __HIP_MEMORY_SCOPE_AGENT);
    if (np > 0) corr_b = ca * ((float)HW_ / (float)np * 0.25f);
  }
  corr_b = wave_sum(corr_b);           // tid<16 all live in wave 0
  if (tid == 0) r1[0] = corr_b;
  __syncthreads();
  if (tid == 0) {
    float obt = r0[0] + r0[1] + r0[2] + r0[3];
    float cft = __hip_atomic_load(&acc->cnt_f, __ATOMIC_RELAXED, __HIP_MEMORY_SCOPE_AGENT);
    float lit = __hip_atomic_load(&acc->liou,  __ATOMIC_RELAXED, __HIP_MEMORY_SCOPE_AGENT);
    float nlt = __hip_atomic_load(&acc->nll,   __ATOMIC_RELAXED, __HIP_MEMORY_SCOPE_AGENT);
    float cBt = __hip_atomic_load(&acc->corrB, __ATOMIC_RELAXED, __HIP_MEMORY_SCOPE_AGENT);
    float corr = r1[0] + cBt;
    float cff = fmaxf(cft, 1.f);
    float iou_loss = lit / cff;
    float cls_loss = nlt / cff;
    float obj_loss = (0.75f * obt + corr) / (float)NHW;
    out[0] = iou_loss;
    out[1] = obj_loss;
    out[2] = cls_loss;
    out[3] = iou_loss * 8.f + obj_loss * 16.f + cls_loss;
  }
}

extern "C" void kernel_launch(void* const* d_in, const int* in_sizes, int n_in,
                              void* d_out, int out_size, void* d_ws, size_t ws_size,
                              hipStream_t stream) {
  const float* preds = (const float*)d_in[0];
  const float* targets = (const float*)d_in[1];
  int M = in_sizes[1] / 6;             // 4096
  int M4 = 4 * M;                      // 16384
  int nact = (M4 + TB - 1) / TB;       // 64

  char* ws = (char*)d_ws;
  size_t off = 0;
  Accum* acc = (Accum*)(ws + off);        off += 256;
  int* winner = (int*)(ws + off);         off += (size_t)NHW * 4;       // 1.6 MB
  float4* state4 = (float4*)(ws + off);   off += (size_t)M4 * 16;       // 256 KB
  float* partA_iou = (float*)(ws + off);  off += ((size_t)nact * 4 + 255) & ~(size_t)255;
  float* partA_cnt = (float*)(ws + off);  off += ((size_t)nact * 4 + 255) & ~(size_t)255;
  float* part_obj = (float*)(ws + off);   off += (size_t)CELLB * 4;

  k1<<<nact + CELLB, TB, 0, stream>>>(preds, targets, M, acc, winner, state4,
                                      partA_iou, partA_cnt, part_obj);
  k2<<<nact, TB, 0, stream>>>(state4, winner, partA_iou, partA_cnt, part_obj,
                              acc, M, nact, (float*)d_out);
}